// Round 5
// baseline (300.601 us; speedup 1.0000x reference)
//
#include <hip/hip_runtime.h>

// GroupTokenizer: y [B,T,C] f32, edges [C,K] f32 -> labels [B,T,C] (as f32), reg [B,T,C,K] f32.
// B=32 T=4096 C=8 K=64. N = B*T*C = 1048576. Output = 272.6 MB -> streaming-store bound.
//
// R9: DECOUPLE bulk bytes from compute. R4-R8 matrix: all full-occupancy coupled
// structures pin at 85-91 us (~3.2 TB/s) while the rocclr fill does 6.27 TB/s on the
// same buffer. Root cause: at 32 w/CU each wave owns only 2 groups -> store runs of
// <=32 before a dependent stall; the fill has unbounded independent runs. Fix: two
// stream-ordered dispatches.
//   A: pure -1 memset of reg region, fill-shaped (grid-stride dwordx4, no reads, no
//      waits) -> fill-speed for 268 MB (~45 us).
//   B: labels (full 256B lines) + ONE 4B delta dword per element scattered into A's
//      region. TCC write-allocates WITHOUT fetch (fill dispatches: 1.09 GB written,
//      FETCH_SIZE ~14 KB) and writes back dirty sectors only -> scatter costs
//      ~4-64 MB, no RMW reads. B ~5-15 us. No shuffles, no drains anywhere.
#define N_ELEM (32 * 4096 * 8)
#define CCH 8
#define KB 64

typedef float vfloat4 __attribute__((ext_vector_type(4)));

// ---- Kernel A: -1 blast over reg region. Mimics __amd_rocclr_fillBufferAligned.
__global__ __launch_bounds__(256) void reg_fill_kernel(float* __restrict__ out,
                                                       long nvec4) {
  const vfloat4 neg1 = {-1.0f, -1.0f, -1.0f, -1.0f};
  vfloat4* v = (vfloat4*)(out + (size_t)N_ELEM);
  const long stride = (long)gridDim.x * blockDim.x;
  for (long i = (long)blockIdx.x * blockDim.x + threadIdx.x; i < nvec4; i += stride) {
    v[i] = neg1;  // independent full-rate stores; wave writes 1KB contiguous per iter
  }
}

// ---- Kernel B: per-wave group: y load -> LDS binary search -> label line + delta dword.
__global__ __launch_bounds__(256) void label_scatter_kernel(
    const float* __restrict__ y,
    const float* __restrict__ le,
    const float* __restrict__ re,
    float* __restrict__ out,
    int ngroups) {
  // Edges in LDS, stride K+1=65 so bank = (c + k) % 32 (distinct across the 8 channels;
  // same-channel lanes hit identical addresses -> broadcast, free).
  __shared__ float ls[CCH][KB + 1];
  __shared__ float rs[CCH][KB + 1];
  const int tid = threadIdx.x;
  for (int t = tid; t < CCH * KB; t += blockDim.x) {
    ls[t >> 6][t & 63] = le[t];
    rs[t >> 6][t & 63] = re[t];
  }
  __syncthreads();

  const int lane = tid & 63;
  const int wid = tid >> 6;
  const int wavesPerBlock = blockDim.x >> 6;
  const int gwave = blockIdx.x * wavesPerBlock + wid;
  const int nwaves = gridDim.x * wavesPerBlock;

  const int c = lane & (CCH - 1);      // e % 8 == lane % 8 (group base divisible by 64)
  const float* lr = ls[c];
  const float* rr = rs[c];

  for (int g = gwave; g < ngroups; g += nwaves) {
    const int e = g * 64 + lane;       // element index (lane-contiguous)
    const float yv = y[e];

    // lower_bound on r: first k with yv < r[k]. 65 possible answers (0..64) ->
    // SEVEN branchless steps (6 left a size-1 interval untested -> earlier absmax bug).
    int lo = 0, hi = KB;
#pragma unroll
    for (int it = 0; it < 7; ++it) {
      const int mid = (lo + hi) >> 1;
      const bool cond = yv < rr[mid];
      hi = cond ? mid : hi;
      lo = cond ? lo : mid + 1;
    }
    // in_bin[lo] iff yv >= l[lo]; otherwise no bin anywhere -> label K-1.
    // (lo==KB read is safe: arrays padded to KB+1.)
    const int label = (lo < KB && yv >= lr[lo]) ? lo : (KB - 1);

    const float left = lr[label];
    const float width = fmaxf(rr[label] - left, 1e-12f);
    float delta = (yv - left) / width;
    delta = fminf(fmaxf(delta, 0.0f), 1.0f);

    // labels output (as float): full 256B lines per wave, coalesced.
    out[e] = (float)label;

    // delta scatter: one dword per element into the A-filled region. Stream order
    // guarantees A completed; write-allocate-no-fetch makes this sector-writeback only.
    out[(size_t)N_ELEM + (size_t)g * (64 * KB) + (size_t)lane * KB + label] = delta;
  }
}

extern "C" void kernel_launch(void* const* d_in, const int* in_sizes, int n_in,
                              void* d_out, int out_size, void* d_ws, size_t ws_size,
                              hipStream_t stream) {
  const float* y = (const float*)d_in[0];
  const float* le = (const float*)d_in[1];
  const float* re = (const float*)d_in[2];
  float* out = (float*)d_out;

  const int n = in_sizes[0];          // 1048576
  const int ngroups = n / 64;         // 16384 wave-tiles
  const long nvec4 = (long)ngroups * (64 * KB) / 4;  // 16.77M float4 = 268.4 MB

  // A: fill-shaped memset. 1024 blocks x 256 thr -> 64 independent dwordx4/thread.
  reg_fill_kernel<<<1024, 256, 0, stream>>>(out, nvec4);

  // B: compute + scatter. 4096 blocks x 4 waves = 16384 waves, 1 group each.
  label_scatter_kernel<<<4096, 256, 0, stream>>>(y, le, re, out, ngroups);
}

// Round 6
// 272.632 us; speedup vs baseline: 1.1026x; 1.1026x over previous
//
#include <hip/hip_runtime.h>

// GroupTokenizer: y [B,T,C] f32, edges [C,K] f32 -> labels [B,T,C] (as f32), reg [B,T,C,K] f32.
// B=32 T=4096 C=8 K=64. N = B*T*C = 1048576. Output = 272.6 MB -> streaming-store bound.
//
// R10: two-pass, both passes full-line coalesced (no scatter -- R9's 4B scatter into
// cold lines caused ~1M partial-line RMW fetches, kernel portion 125 us, worst yet).
// Discriminates the two surviving theories for R4/R5/R8's flat ~88 us:
//   T-A: ~40 us fixed harness overhead beyond the poison fill; kernels already at the
//        ~44 us write roofline -> this version lands ~285, revert+ROOFLINE next.
//   T-B: coupled per-wave 16KB ownership caps write BW at 3.2 TB/s; a fill-shaped
//        sweep does 6.27 -> this version lands ~240-250.
// Pass 1: per-element LDS binary search -> labels (output, 4MB) + deltas (d_ws, 4MB),
//         fully coalesced. ~10 us.
// Pass 2: grid-stride dwordx4 sweep over the 268MB reg region (structurally identical
//         to the 6.27 TB/s rocclr fill); each float4 composed from 2 broadcast dwords
//         (label from labels output, delta from d_ws; 4 distinct dwords/wave, L2-warm).
//         No LDS, no shuffles, no waits.
// Fallback if ws_size < 4MB: proven single-pass R8 kernel (88 us).
#define N_ELEM (32 * 4096 * 8)
#define CCH 8
#define KB 64

typedef float vfloat4 __attribute__((ext_vector_type(4)));

// ---- Pass 1: search -> labels + deltas (all coalesced 4B/lane).
__global__ __launch_bounds__(256) void search_kernel(
    const float* __restrict__ y,
    const float* __restrict__ le,
    const float* __restrict__ re,
    float* __restrict__ labels_out,
    float* __restrict__ deltas_out,
    int nelem) {
  __shared__ float ls[CCH][KB + 1];
  __shared__ float rs[CCH][KB + 1];
  const int tid = threadIdx.x;
  for (int t = tid; t < CCH * KB; t += blockDim.x) {
    ls[t >> 6][t & 63] = le[t];
    rs[t >> 6][t & 63] = re[t];
  }
  __syncthreads();

  const int stride = gridDim.x * blockDim.x;
  for (int e = blockIdx.x * blockDim.x + tid; e < nelem; e += stride) {
    const float yv = y[e];
    const int c = e & (CCH - 1);
    const float* lr = ls[c];
    const float* rr = rs[c];

    // lower_bound on r: first k with yv < r[k]. 65 possible answers (0..64) ->
    // SEVEN branchless steps (6 left a size-1 interval untested -> earlier absmax bug).
    int lo = 0, hi = KB;
#pragma unroll
    for (int it = 0; it < 7; ++it) {
      const int mid = (lo + hi) >> 1;
      const bool cond = yv < rr[mid];
      hi = cond ? mid : hi;
      lo = cond ? lo : mid + 1;
    }
    // (lo==KB read is safe: arrays padded to KB+1.)
    const int label = (lo < KB && yv >= lr[lo]) ? lo : (KB - 1);
    const float left = lr[label];
    const float width = fmaxf(rr[label] - left, 1e-12f);
    const float delta = fminf(fmaxf((yv - left) / width, 0.0f), 1.0f);

    labels_out[e] = (float)label;
    deltas_out[e] = delta;
  }
}

// ---- Pass 2: fill-shaped sweep composing reg on the fly. reg is flat [N_ELEM][64]:
// float4 index i -> element e = i>>4, k-base k0 = (i&15)*4.
__global__ __launch_bounds__(256) void compose_sweep_kernel(
    const float* __restrict__ labels,
    const float* __restrict__ deltas,
    float* __restrict__ reg,
    long nvec4) {
  vfloat4* v = (vfloat4*)reg;
  const long stride = (long)gridDim.x * blockDim.x;
  for (long i = (long)blockIdx.x * blockDim.x + threadIdx.x; i < nvec4; i += stride) {
    const int e = (int)(i >> 4);
    const int k0 = ((int)i & 15) << 2;
    const int lbl = (int)labels[e];     // 4 distinct dwords per wave (broadcast), L2-warm
    const float dlt = deltas[e];
    vfloat4 v4;
    v4.x = (k0 + 0 == lbl) ? dlt : -1.0f;
    v4.y = (k0 + 1 == lbl) ? dlt : -1.0f;
    v4.z = (k0 + 2 == lbl) ? dlt : -1.0f;
    v4.w = (k0 + 3 == lbl) ? dlt : -1.0f;
    v[i] = v4;                          // 1KB/wave/instr, unbounded independent stream
  }
}

// ---- Fallback: proven single-pass (R8 structure, ~88 us), used if d_ws too small.
#define GPW 2
#define WPB 4
__global__ __launch_bounds__(256) void group_tokenizer_fallback(
    const float* __restrict__ y,
    const float* __restrict__ le,
    const float* __restrict__ re,
    float* __restrict__ out,
    int ngroups) {
  __shared__ float ls[CCH][KB + 1];
  __shared__ float rs[CCH][KB + 1];
  const int tid = threadIdx.x;
  for (int t = tid; t < CCH * KB; t += blockDim.x) {
    ls[t >> 6][t & 63] = le[t];
    rs[t >> 6][t & 63] = re[t];
  }
  __syncthreads();

  const int lane = tid & 63;
  const int wid = tid >> 6;
  const int g0 = (blockIdx.x * WPB + wid) * GPW;
  if (g0 >= ngroups) return;

  const int c = lane & (CCH - 1);
  const float* lr = ls[c];
  const float* rr = rs[c];

  int labelA[GPW];
  float deltaA[GPW];
#pragma unroll
  for (int t = 0; t < GPW; ++t) {
    const int g = g0 + t;
    const float yv = (g < ngroups) ? y[g * 64 + lane] : 0.0f;
    int lo = 0, hi = KB;
#pragma unroll
    for (int it = 0; it < 7; ++it) {
      const int mid = (lo + hi) >> 1;
      const bool cond = yv < rr[mid];
      hi = cond ? mid : hi;
      lo = cond ? lo : mid + 1;
    }
    const int label = (lo < KB && yv >= lr[lo]) ? lo : (KB - 1);
    const float left = lr[label];
    const float width = fmaxf(rr[label] - left, 1e-12f);
    labelA[t] = label;
    deltaA[t] = fminf(fmaxf((yv - left) / width, 0.0f), 1.0f);
  }

#pragma unroll
  for (int t = 0; t < GPW; ++t) {
    const int g = g0 + t;
    if (g < ngroups) out[g * 64 + lane] = (float)labelA[t];
  }

  const int kst = (lane & 15) << 2;
#pragma unroll
  for (int t = 0; t < GPW; ++t) {
    const int g = g0 + t;
    if (g >= ngroups) break;
    vfloat4* regv = (vfloat4*)(out + (size_t)N_ELEM + (size_t)g * (64 * KB));
    const int label = labelA[t];
    const float delta = deltaA[t];
#pragma unroll
    for (int j = 0; j < 16; ++j) {
      const int src = (j << 2) + (lane >> 4);
      const int lbl = __shfl(label, src, 64);
      const float dlt = __shfl(delta, src, 64);
      vfloat4 v;
      v.x = (kst + 0 == lbl) ? dlt : -1.0f;
      v.y = (kst + 1 == lbl) ? dlt : -1.0f;
      v.z = (kst + 2 == lbl) ? dlt : -1.0f;
      v.w = (kst + 3 == lbl) ? dlt : -1.0f;
      regv[(j << 6) + lane] = v;
    }
  }
}

extern "C" void kernel_launch(void* const* d_in, const int* in_sizes, int n_in,
                              void* d_out, int out_size, void* d_ws, size_t ws_size,
                              hipStream_t stream) {
  const float* y = (const float*)d_in[0];
  const float* le = (const float*)d_in[1];
  const float* re = (const float*)d_in[2];
  float* out = (float*)d_out;

  const int n = in_sizes[0];          // 1048576
  const int ngroups = n / 64;         // 16384

  if (d_ws != nullptr && ws_size >= (size_t)n * sizeof(float)) {
    float* deltas = (float*)d_ws;
    // Pass 1: 2048 blocks x 256 -> full occupancy, 2 elems/thread grid-strided.
    search_kernel<<<2048, 256, 0, stream>>>(y, le, re, out, deltas, n);
    // Pass 2: fill-shaped sweep over 268 MB (16.77M float4).
    const long nvec4 = (long)n * KB / 4;
    compose_sweep_kernel<<<1024, 256, 0, stream>>>(out, deltas, out + (size_t)N_ELEM,
                                                   nvec4);
  } else {
    const int gpb = WPB * GPW;
    const int blocks = (ngroups + gpb - 1) / gpb;  // 2048
    group_tokenizer_fallback<<<blocks, 256, 0, stream>>>(y, le, re, out, ngroups);
  }
}

// Round 7
// 266.878 us; speedup vs baseline: 1.1264x; 1.0216x over previous
//
#include <hip/hip_runtime.h>

// GroupTokenizer: y [B,T,C] f32, edges [C,K] f32 -> labels [B,T,C] (as f32), reg [B,T,C,K] f32.
// B=32 T=4096 C=8 K=64. N = B*T*C = 1048576. Output = 272.6 MB -> streaming-store bound.
//
// R11 = REVERT to R8 (best on record: 266.2 us, absmax 0). Final structure record
// (kernel-portion us, normalized against each run's 1.09GB rocclr-fill reference
// which sustains 6.27 TB/s pure-write):
//   R4 interleaved compose 32w/CU: 91   R5 blast+scatter 32w/CU: 85
//   R6 blast+scatter 16w/CU: 113        R7 phase-split 16w/CU: 104
//   R8 phase-split 32w/CU: 88           R9 fill+cold-scatter: 125 (RMW disaster)
//   R10 two-pass fill-shaped sweep: ~100 (even a load-light fill-identical sweep
//                                         runs at ~3.1 TB/s, not 6.27)
// Conclusion: any kernel with per-element data dependence writes this buffer at
// ~3.2 TB/s; only a pure value-fill reaches 6.27. Structure (occupancy, stream
// count, phase split, load coupling) is exhausted. This is the roofline candidate.
//
// Structure: 2048 blocks (exactly 8 blk/CU = 32 w/CU resident), 4 waves/block,
// 2 contiguous groups/wave. Phase A: both y-loads in flight + both 7-deep LDS
// binary searches interleaved (independent chains -> ILP). Phase B: one burst of
// 2 full-line label stores + 32 shuffle-composed dwordx4 reg stores (32.5 KB
// contiguous per wave). No scatter, no vmcnt drains, no partial lines.
#define N_ELEM (32 * 4096 * 8)
#define CCH 8
#define KB 64
#define GPW 2   // groups per wave (2048 blocks x 4 waves x 2 = 16384 groups exactly)
#define WPB 4   // waves per block (256 threads)

typedef float vfloat4 __attribute__((ext_vector_type(4)));

__global__ __launch_bounds__(256) void group_tokenizer_kernel(
    const float* __restrict__ y,
    const float* __restrict__ le,
    const float* __restrict__ re,
    float* __restrict__ out,
    int ngroups) {
  // Edges in LDS, stride K+1=65 so bank = (c + k) % 32 (distinct across the 8 channels;
  // same-channel lanes hit identical addresses -> broadcast, free).
  __shared__ float ls[CCH][KB + 1];
  __shared__ float rs[CCH][KB + 1];
  const int tid = threadIdx.x;
  for (int t = tid; t < CCH * KB; t += blockDim.x) {
    ls[t >> 6][t & 63] = le[t];
    rs[t >> 6][t & 63] = re[t];
  }
  __syncthreads();

  const int lane = tid & 63;
  const int wid = tid >> 6;
  const int g0 = (blockIdx.x * WPB + wid) * GPW;
  if (g0 >= ngroups) return;

  const int c = lane & (CCH - 1);      // e % 8 == lane % 8 (group base divisible by 64)
  const float* lr = ls[c];
  const float* rr = rs[c];

  // ---- Phase A: both y-loads in flight together, then both searches interleaved
  // (independent 7-deep LDS chains overlap -> ~half the exposed search latency).
  int labelA[GPW];
  float deltaA[GPW];
#pragma unroll
  for (int t = 0; t < GPW; ++t) {
    const int g = g0 + t;
    const float yv = (g < ngroups) ? y[g * 64 + lane] : 0.0f;

    // lower_bound on r: first k with yv < r[k]. 65 possible answers (0..64) ->
    // SEVEN branchless steps (6 left a size-1 interval untested -> earlier absmax bug).
    int lo = 0, hi = KB;
#pragma unroll
    for (int it = 0; it < 7; ++it) {
      const int mid = (lo + hi) >> 1;
      const bool cond = yv < rr[mid];
      hi = cond ? mid : hi;
      lo = cond ? lo : mid + 1;
    }
    // in_bin[lo] iff yv >= l[lo]; otherwise no bin anywhere -> label K-1.
    // (lo==KB read is safe: arrays padded to KB+1.)
    const int label = (lo < KB && yv >= lr[lo]) ? lo : (KB - 1);
    const float left = lr[label];
    const float width = fmaxf(rr[label] - left, 1e-12f);
    labelA[t] = label;
    deltaA[t] = fminf(fmaxf((yv - left) / width, 0.0f), 1.0f);
  }

  // ---- Phase B: one store burst. 2 label lines + 32 composed dwordx4 (32.5 KB).
#pragma unroll
  for (int t = 0; t < GPW; ++t) {
    const int g = g0 + t;
    if (g < ngroups) out[g * 64 + lane] = (float)labelA[t];
  }

  const int kst = (lane & 15) << 2;    // this lane's k-offset within its element
#pragma unroll
  for (int t = 0; t < GPW; ++t) {
    const int g = g0 + t;
    if (g >= ngroups) break;
    vfloat4* regv = (vfloat4*)(out + (size_t)N_ELEM + (size_t)g * (64 * KB));
    const int label = labelA[t];
    const float delta = deltaA[t];
#pragma unroll
    for (int j = 0; j < 16; ++j) {
      const int src = (j << 2) + (lane >> 4);   // which lane's element this float4 belongs to
      const int lbl = __shfl(label, src, 64);
      const float dlt = __shfl(delta, src, 64);
      vfloat4 v;
      v.x = (kst + 0 == lbl) ? dlt : -1.0f;
      v.y = (kst + 1 == lbl) ? dlt : -1.0f;
      v.z = (kst + 2 == lbl) ? dlt : -1.0f;
      v.w = (kst + 3 == lbl) ? dlt : -1.0f;
      regv[(j << 6) + lane] = v;
    }
  }
}

extern "C" void kernel_launch(void* const* d_in, const int* in_sizes, int n_in,
                              void* d_out, int out_size, void* d_ws, size_t ws_size,
                              hipStream_t stream) {
  const float* y = (const float*)d_in[0];
  const float* le = (const float*)d_in[1];
  const float* re = (const float*)d_in[2];
  float* out = (float*)d_out;

  const int n = in_sizes[0];          // 1048576
  const int ngroups = n / 64;         // 16384 wave-tiles
  const int gpb = WPB * GPW;          // 8 groups per block
  const int blocks = (ngroups + gpb - 1) / gpb;  // 2048 -> exactly 8 blk/CU, 32 w/CU

  group_tokenizer_kernel<<<blocks, 256, 0, stream>>>(y, le, re, out, ngroups);
}